// Round 12
// baseline (1212.613 us; speedup 1.0000x reference)
//
#include <hip/hip_runtime.h>
#include <cstdint>
#include <cstddef>

typedef __attribute__((ext_vector_type(8))) short short8;
typedef __attribute__((ext_vector_type(4))) float floatx4;
typedef __attribute__((ext_vector_type(2))) float floatx2;
typedef __attribute__((ext_vector_type(4))) int intx4;

static constexpr int DIN  = 64;
static constexpr int DHID = 128;
static constexpr int BSH  = 7;               // 128 nodes per dst-bucket
static constexpr int BNODES = 1 << BSH;
static constexpr int TILE = 8192;            // edges per partition block
static constexpr int CAP  = 4096;            // bucket region capacity
static constexpr int EPT  = TILE / 512;      // 16 edges per thread (register-held)
static constexpr unsigned SENT = 0xFFFFFFFFu;

__device__ inline short f2bf(float f) {      // RNE float->bf16
  unsigned u = __float_as_uint(f);
  u += 0x7FFF + ((u >> 16) & 1);
  return (short)(u >> 16);
}
__device__ inline float bf2f(short s) {
  return __uint_as_float(((unsigned)(unsigned short)s) << 16);
}

// ====================== fused partition + prep (512 threads, staged writes) ============
// blocks [0,gP): edge partition, TILE=8192, EPT=16 register-held; LDS-staged
// run-coalesced writes to packed (padded-to-16 runs, SENT sentinels).
// real_cnt REMOVED (no CSR downstream anymore) -> 123K fewer global atomics.
// blocks [gP,gP+gx): x cast. blocks [gP+gx, gP+gx+16): weight concat.
// wc1[n][k] = [Wl1 | Wr1] (K-concat), wc2[n][k] = rows [Wl2 ; Wr2] (N-concat).
__global__ __launch_bounds__(512) void part_prep_kernel(const void* edges, long long nmax,
    int* __restrict__ bucket_cursor,
    unsigned* __restrict__ packed, int E, int NB,
    const float* __restrict__ x,
    const float* __restrict__ Wl1, const float* __restrict__ Wr1,
    const float* __restrict__ Wl2, const float* __restrict__ Wr2,
    short* __restrict__ xb, short* __restrict__ wc1, short* __restrict__ wc2,
    int nx, int gP, int gx)
{
  __shared__ unsigned sval[TILE];           // 32KB: locally bucket-sorted payloads
  __shared__ unsigned short sbid[TILE];     // 16KB: bucket id per sorted slot
  __shared__ int hist[1024];
  __shared__ int lbase[1024];               // block-local exclusive prefix
  __shared__ int gb[1024];                  // global run base per bucket
  __shared__ int wsum[8];
  __shared__ int smode;
  int t = threadIdx.x;
  int blk = blockIdx.x;
  if (blk >= gP) {                       // ---- prep part ----
    int b = blk - gP;
    if (b < gx) {
      int i0 = (b * 512 + t) * 8;
      if (i0 < nx) {  // nx % 8 == 0
        floatx4 f0 = *(const floatx4*)&x[i0];
        floatx4 f1 = *(const floatx4*)&x[i0 + 4];
        short8 o;
        o[0]=f2bf(f0[0]); o[1]=f2bf(f0[1]); o[2]=f2bf(f0[2]); o[3]=f2bf(f0[3]);
        o[4]=f2bf(f1[0]); o[5]=f2bf(f1[1]); o[6]=f2bf(f1[2]); o[7]=f2bf(f1[3]);
        *(short8*)&xb[i0] = o;
      }
    } else {
      int wb = b - gx;                       // 0..15
      int idx = ((wb & 7) * 512 + t) * 4;    // 0..16383
      int n = idx >> 7, k = idx & 127;
      const float* src;
      if (wb < 8) src = (k < 64) ? &Wl1[n * 64 + k] : &Wr1[n * 64 + (k - 64)];
      else        src = (n < 64) ? &Wl2[n * 128 + k] : &Wr2[(n - 64) * 128 + k];
      floatx4 f = *(const floatx4*)src;
      short* dst = (wb < 8 ? wc1 : wc2) + idx;
      dst[0]=f2bf(f[0]); dst[1]=f2bf(f[1]); dst[2]=f2bf(f[2]); dst[3]=f2bf(f[3]);
    }
    return;
  }
  // ---- partition part ----
  int base = blk * TILE;
  int cnt_here = E - base; if (cnt_here > TILE) cnt_here = TILE;
  for (int i = t; i < NB; i += 512) hist[i] = 0;
  if (t == 0) smode = 1;
  __syncthreads();
  {
    const long long* e64 = (const long long*)edges;
    int nchk = E < 256 ? E : 256;
    bool ok = true;
    for (int i = t; i < nchk; i += 512) {
      long long v = e64[i];
      if (v < 0 || v >= nmax) ok = false;
    }
    if (!ok) smode = 0;   // idempotent race, fine
  }
  __syncthreads();
  bool m64 = (smode != 0);
  // ---- pass 1: load tile into registers, rank via LDS atomic ----
  unsigned val[EPT];   // payload: (d&127)<<17 | s
  unsigned aux[EPT];   // (b<<13) | rank   (rank < 8192)
  #pragma unroll
  for (int c = 0; c < EPT; ++c) {
    int idx = c * 512 + t;
    val[c] = 0; aux[c] = 0;
    if (idx < cnt_here) {
      int i = base + idx;
      int s, d;
      if (m64) { const long long* e = (const long long*)edges; s = (int)e[i]; d = (int)e[(size_t)E + i]; }
      else     { const int*       e = (const int*)edges;       s = e[i];      d = e[(size_t)E + i]; }
      int b = d >> BSH;
      int rank = atomicAdd(&hist[b], 1);
      val[c] = ((unsigned)(d & (BNODES - 1)) << 17) | (unsigned)s;
      aux[c] = ((unsigned)b << 13) | (unsigned)rank;
    }
  }
  __syncthreads();
  // ---- block scan of hist -> lbase; padded global run reservation + SENT fill ----
  {
    int i0 = t * 2;
    int v2[2]; int s = 0;
    #pragma unroll
    for (int c = 0; c < 2; ++c) { int idx = i0 + c; v2[c] = (idx < NB) ? hist[idx] : 0; s += v2[c]; }
    int lane = t & 63, w = t >> 6;
    int vv = s;
    #pragma unroll
    for (int off = 1; off < 64; off <<= 1) {
      int u = __shfl_up(vv, off, 64);
      if (lane >= off) vv += u;
    }
    if (lane == 63) wsum[w] = vv;
    __syncthreads();
    int wpre = 0;
    for (int ww = 0; ww < w; ++ww) wpre += wsum[ww];
    int run = wpre + vv - s;
    #pragma unroll
    for (int c = 0; c < 2; ++c) {
      int idx = i0 + c;
      if (idx < NB) {
        int cnt = v2[c];
        lbase[idx] = run;
        int gbase = 0;
        if (cnt > 0) {
          int pad = (cnt + 15) & ~15;
          gbase = idx * CAP + atomicAdd(&bucket_cursor[idx], pad);
          for (int j = cnt; j < pad; ++j) packed[gbase + j] = SENT;
        }
        gb[idx] = gbase;
        run += cnt;
      }
    }
  }
  __syncthreads();
  // ---- LDS scatter into bucket-sorted order ----
  #pragma unroll
  for (int c = 0; c < EPT; ++c) {
    int idx = c * 512 + t;
    if (idx < cnt_here) {
      int b = (int)(aux[c] >> 13);
      int r = (int)(aux[c] & 0x1FFFu);
      int p = lbase[b] + r;
      sval[p] = val[c];
      sbid[p] = (unsigned short)b;
    }
  }
  __syncthreads();
  // ---- linear, run-coalesced global write ----
  #pragma unroll
  for (int c = 0; c < EPT; ++c) {
    int i = c * 512 + t;
    if (i < cnt_here) {
      int b = (int)sbid[i];
      packed[gb[b] + (i - lbase[b])] = sval[i];
    }
  }
}

// ====================== mean aggregation DIRECT from packed (no CSR) ===================
// Block b owns bucket b (nodes [b*128,(b+1)*128)). 8 lanes per edge: lane c gathers
// 16B of feat[src] and fire-and-forget LDS-atomic-adds into accum[d_local][c*8..].
// Degrees counted in LDS. 33KB LDS, 512 thr -> 4 blocks/CU = 32 waves/CU (full).
// Eliminates counting sort, sorted_src, row_ptr entirely.
// EPI: out = mean + bias + r (fp32), else bf16 mean out.
template <bool EPI>
__global__ __launch_bounds__(512) void agg_packed_kernel(const unsigned* __restrict__ packed,
    const int* __restrict__ bucket_cursor,
    const short* __restrict__ feat,
    const float* __restrict__ rbuf, const float* __restrict__ bias,
    short* __restrict__ outb, float* __restrict__ outf, int N)
{
  __shared__ float accum[BNODES][64];   // 32KB
  __shared__ int   cnt[BNODES];
  int b = blockIdx.x, t = threadIdx.x;
  // ---- zero ----
  {
    floatx4 z = (floatx4){0.f, 0.f, 0.f, 0.f};
    float* a0 = (float*)accum;
    #pragma unroll
    for (int i = 0; i < 4; ++i)
      *(floatx4*)&a0[(i * 512 + t) * 4] = z;
    if (t < BNODES) cnt[t] = 0;
  }
  __syncthreads();
  int rbeg = b * CAP, rcnt = bucket_cursor[b];
  int g = t >> 3, c = t & 7;
  const short* fbase = feat + c * 8;
  // ---- edge loop: 64 edges in flight per iteration ----
  for (int i = g; i < rcnt; i += 64) {
    unsigned p = packed[rbeg + i];
    if (p != SENT) {
      int dl = (int)(p >> 17);
      int s  = (int)(p & 0x1FFFFu);
      short8 v = *(const short8*)&fbase[(size_t)s * 64];
      float* ap = &accum[dl][c * 8];
      #pragma unroll
      for (int j = 0; j < 8; ++j) atomicAdd(&ap[j], bf2f(v[j]));   // ds_add_f32, no return
      if (c == 0) atomicAdd(&cnt[dl], 1);
    }
  }
  __syncthreads();
  // ---- emit means: 8 lanes per node, 64 nodes per chunk ----
  int n0 = b << BSH;
  int ln = t >> 3;
  #pragma unroll
  for (int ch = 0; ch < 2; ++ch) {
    int nl = ch * 64 + ln;
    int node = n0 + nl;
    if (node < N) {
      float inv = 1.f / fmaxf((float)cnt[nl], 1.f);
      const float* ap = &accum[nl][c * 8];
      if (!EPI) {
        short8 o;
        #pragma unroll
        for (int j = 0; j < 8; ++j) o[j] = f2bf(ap[j] * inv);
        *(short8*)&outb[(size_t)node * 64 + c * 8] = o;
      } else {
        floatx4 b0 = *(const floatx4*)&bias[c * 8];
        floatx4 b1 = *(const floatx4*)&bias[c * 8 + 4];
        floatx4 r0 = *(const floatx4*)&rbuf[(size_t)node * 64 + c * 8];
        floatx4 r1 = *(const floatx4*)&rbuf[(size_t)node * 64 + c * 8 + 4];
        floatx4 o0, o1;
        #pragma unroll
        for (int j = 0; j < 4; ++j) {
          o0[j] = ap[j] * inv + b0[j] + r0[j];
          o1[j] = ap[4 + j] * inv + b1[j] + r1[j];
        }
        *(floatx4*)&outf[(size_t)node * 64 + c * 8]     = o0;
        *(floatx4*)&outf[(size_t)node * 64 + c * 8 + 4] = o1;
      }
    }
  }
}

// ====================== fused bf16 MFMA GEMM: layer1 -> (LDS h) -> layer2 ==============
// 128 rows/block (2 m-tiles per wave) to amortize the 64KB weight staging.
// Phase 1: h = relu([mean|x] @ wc1^T + bl1) -> LDS Hs (never hits HBM).
// Phase 2: restage Ws with wc2; cols 0..63 -> g bf16, cols 64..127 -> r fp32.
// A-frag: lane holds A[m=lane&15][k=q*8..q*8+7]; C/D: col=lane&15, row=q*4+reg (m89).
// Row-pad 136 shorts: 2-way bank alias on ds_read_b128 = free (m136).
__global__ __launch_bounds__(256) void fused_gemm_kernel(
    const short* __restrict__ Aa, const short* __restrict__ Ab,
    const short* __restrict__ wc1, const short* __restrict__ wc2,
    const float* __restrict__ bias1,
    short* __restrict__ Cg, float* __restrict__ Cr, int M)
{
  __shared__ short Ws[128][136];
  __shared__ short Hs[128][136];
  int t = threadIdx.x;
  // ---- stage wc1 ----
  #pragma unroll
  for (int i = 0; i < 8; ++i) {
    int idx = i * 256 + t;
    int r = idx >> 4, c8 = (idx & 15) * 8;
    *(short8*)&Ws[r][c8] = *(const short8*)&wc1[r * 128 + c8];
  }
  __syncthreads();
  int wv = t >> 6, lane = t & 63, q = lane >> 4, l15 = lane & 15;
  int m0 = blockIdx.x * 128 + wv * 32;
  floatx4 acc[2][8];
  #pragma unroll
  for (int mt = 0; mt < 2; ++mt)
    #pragma unroll
    for (int nt = 0; nt < 8; ++nt) acc[mt][nt] = (floatx4){0.f, 0.f, 0.f, 0.f};
  // ---- phase 1: [mean | x] @ wc1^T ----
  #pragma unroll
  for (int ko = 0; ko < 4; ++ko) {
    const short* Asrc = (ko < 2) ? Aa : Ab;
    short8 a[2];
    #pragma unroll
    for (int mt = 0; mt < 2; ++mt) {
      int row = m0 + mt * 16 + l15;
      a[mt] = (short8){0, 0, 0, 0, 0, 0, 0, 0};
      if (row < M) a[mt] = *(const short8*)&Asrc[(size_t)row * 64 + (ko & 1) * 32 + q * 8];
    }
    #pragma unroll
    for (int nt = 0; nt < 8; ++nt) {
      short8 bfr = *(const short8*)&Ws[nt * 16 + l15][ko * 32 + q * 8];
      acc[0][nt] = __builtin_amdgcn_mfma_f32_16x16x32_bf16(a[0], bfr, acc[0][nt], 0, 0, 0);
      acc[1][nt] = __builtin_amdgcn_mfma_f32_16x16x32_bf16(a[1], bfr, acc[1][nt], 0, 0, 0);
    }
  }
  // ---- epilogue 1: relu(+bias) -> Hs (block-local rows) ----
  #pragma unroll
  for (int mt = 0; mt < 2; ++mt) {
    #pragma unroll
    for (int nt = 0; nt < 8; ++nt) {
      int n = nt * 16 + l15;
      float bv = bias1[n];
      #pragma unroll
      for (int r2 = 0; r2 < 4; ++r2) {
        int lr = wv * 32 + mt * 16 + q * 4 + r2;   // block-local row
        float v = fmaxf(acc[mt][nt][r2] + bv, 0.f);
        Hs[lr][n] = f2bf(v);
      }
    }
  }
  __syncthreads();               // Ws reads done everywhere; Hs visible
  // ---- restage Ws with wc2 ----
  #pragma unroll
  for (int i = 0; i < 8; ++i) {
    int idx = i * 256 + t;
    int r = idx >> 4, c8 = (idx & 15) * 8;
    *(short8*)&Ws[r][c8] = *(const short8*)&wc2[r * 128 + c8];
  }
  __syncthreads();
  // ---- phase 2: h @ wc2^T (A from LDS) ----
  #pragma unroll
  for (int mt = 0; mt < 2; ++mt)
    #pragma unroll
    for (int nt = 0; nt < 8; ++nt) acc[mt][nt] = (floatx4){0.f, 0.f, 0.f, 0.f};
  #pragma unroll
  for (int ko = 0; ko < 4; ++ko) {
    short8 a[2];
    #pragma unroll
    for (int mt = 0; mt < 2; ++mt)
      a[mt] = *(const short8*)&Hs[wv * 32 + mt * 16 + l15][ko * 32 + q * 8];
    #pragma unroll
    for (int nt = 0; nt < 8; ++nt) {
      short8 bfr = *(const short8*)&Ws[nt * 16 + l15][ko * 32 + q * 8];
      acc[0][nt] = __builtin_amdgcn_mfma_f32_16x16x32_bf16(a[0], bfr, acc[0][nt], 0, 0, 0);
      acc[1][nt] = __builtin_amdgcn_mfma_f32_16x16x32_bf16(a[1], bfr, acc[1][nt], 0, 0, 0);
    }
  }
  // ---- epilogue 2: cols 0..63 -> Cg bf16, cols 64..127 -> Cr fp32 ----
  #pragma unroll
  for (int mt = 0; mt < 2; ++mt) {
    #pragma unroll
    for (int nt = 0; nt < 8; ++nt) {
      int n = nt * 16 + l15;
      #pragma unroll
      for (int r2 = 0; r2 < 4; ++r2) {
        int mr = m0 + mt * 16 + q * 4 + r2;
        if (mr >= M) continue;
        float v = acc[mt][nt][r2];
        if (nt < 4) Cg[(size_t)mr * 64 + n] = f2bf(v);
        else        Cr[(size_t)mr * 64 + (n - 64)] = v;
      }
    }
  }
}

// ====================== launch ======================
extern "C" void kernel_launch(void* const* d_in, const int* in_sizes, int n_in,
                              void* d_out, int out_size, void* d_ws, size_t ws_size,
                              hipStream_t stream) {
  const float* x   = (const float*)d_in[0];
  const void*  ei  = d_in[1];
  const float* Wl1 = (const float*)d_in[2];
  const float* bl1 = (const float*)d_in[3];
  const float* Wr1 = (const float*)d_in[4];
  const float* Wl2 = (const float*)d_in[5];
  const float* bl2 = (const float*)d_in[6];
  const float* Wr2 = (const float*)d_in[7];
  int N = in_sizes[0] / DIN;
  int E = in_sizes[1] / 2;
  int NB = (N + BNODES - 1) / BNODES;

  char* w = (char*)d_ws;
  size_t off = 0;
  auto alloc = [&](size_t bytes) -> void* {
    void* p = w + off;
    off += (bytes + 255) & ~(size_t)255;
    return p;
  };
  int*      bcur       = (int*)alloc((size_t)NB * 4);      // padded per-bucket cursors
  unsigned* packed     = (unsigned*)alloc((size_t)NB * CAP * 4);
  short*    xb         = (short*)alloc((size_t)N * 64 * 2);
  short*    meanb      = (short*)alloc((size_t)N * 64 * 2);  // layer-1 mean, reused as g
  float*    rbuf       = (float*)alloc((size_t)N * 64 * 4);
  short*    wc1        = (short*)alloc(128 * 128 * 2);
  short*    wc2        = (short*)alloc(128 * 128 * 2);
  (void)ws_size; (void)n_in; (void)out_size;

  hipMemsetAsync(bcur, 0, (size_t)NB * 4, stream);

  int nx = N * DIN;
  int gx = (nx / 8 + 511) / 512;
  int gP = (E + TILE - 1) / TILE;
  part_prep_kernel<<<gP + gx + 16, 512, 0, stream>>>(ei, (long long)N, bcur, packed,
                                                     E, NB, x, Wl1, Wr1, Wl2, Wr2,
                                                     xb, wc1, wc2, nx, gP, gx);

  agg_packed_kernel<false><<<NB, 512, 0, stream>>>(packed, bcur, xb,
                                                   nullptr, nullptr, meanb, nullptr, N);

  int gm = (N + 127) / 128;
  fused_gemm_kernel<<<gm, 256, 0, stream>>>(meanb, xb, wc1, wc2, bl1, meanb, rbuf, N);

  agg_packed_kernel<true><<<NB, 512, 0, stream>>>(packed, bcur, meanb,
                                                  rbuf, bl2, nullptr, (float*)d_out, N);
}

// Round 13
// 200.372 us; speedup vs baseline: 6.0518x; 6.0518x over previous
//
#include <hip/hip_runtime.h>
#include <cstdint>
#include <cstddef>

typedef __attribute__((ext_vector_type(8))) short short8;
typedef __attribute__((ext_vector_type(4))) float floatx4;
typedef __attribute__((ext_vector_type(2))) float floatx2;
typedef __attribute__((ext_vector_type(4))) int intx4;

static constexpr int DIN  = 64;
static constexpr int DHID = 128;
static constexpr int BSH  = 7;               // 128 nodes per dst-bucket
static constexpr int BNODES = 1 << BSH;
static constexpr int TILE = 16384;           // edges per partition block (halves contended atomics)
static constexpr int CAP  = 4096;            // bucket region capacity
static constexpr int EPT  = TILE / 512;      // 32 edges per thread (register-held)
static constexpr unsigned SENT = 0xFFFFFFFFu;

__device__ inline short f2bf(float f) {      // RNE float->bf16
  unsigned u = __float_as_uint(f);
  u += 0x7FFF + ((u >> 16) & 1);
  return (short)(u >> 16);
}
__device__ inline float bf2f(short s) {
  return __uint_as_float(((unsigned)(unsigned short)s) << 16);
}
// one u32 holding bf16 pair (elem 2k low, 2k+1 high) -> 2 f32
__device__ inline floatx2 bfpair(unsigned u) {
  floatx2 r;
  r[0] = __uint_as_float(u << 16);
  r[1] = __uint_as_float(u & 0xFFFF0000u);
  return r;
}

// ====================== fused partition + prep (512 threads, TILE=16384) ===============
// blocks [0,gP): edge partition, EPT=32 register-held, direct register->global scatter
// (r11 showed staged == direct). TILE=16384 halves the contended bucket_cursor atomics
// (79 blocks x 782 buckets ~= 62K returned global atomics vs 123K at TILE=8192).
// LDS = hist+gb ~8KB only.
// blocks [gP,gP+gx): x cast. blocks [gP+gx, gP+gx+16): weight concat.
// wc1[n][k] = [Wl1 | Wr1] (K-concat), wc2[n][k] = rows [Wl2 ; Wr2] (N-concat).
__global__ __launch_bounds__(512) void part_prep_kernel(const void* edges, long long nmax,
    int* __restrict__ bucket_cursor, int* __restrict__ real_cnt,
    unsigned* __restrict__ packed, int E, int NB,
    const float* __restrict__ x,
    const float* __restrict__ Wl1, const float* __restrict__ Wr1,
    const float* __restrict__ Wl2, const float* __restrict__ Wr2,
    short* __restrict__ xb, short* __restrict__ wc1, short* __restrict__ wc2,
    int nx, int gP, int gx)
{
  __shared__ int hist[1024];
  __shared__ int gb[1024];
  __shared__ int smode;
  int t = threadIdx.x;
  int blk = blockIdx.x;
  if (blk >= gP) {                       // ---- prep part ----
    int b = blk - gP;
    if (b < gx) {
      int i0 = (b * 512 + t) * 8;
      if (i0 < nx) {  // nx % 8 == 0
        floatx4 f0 = *(const floatx4*)&x[i0];
        floatx4 f1 = *(const floatx4*)&x[i0 + 4];
        short8 o;
        o[0]=f2bf(f0[0]); o[1]=f2bf(f0[1]); o[2]=f2bf(f0[2]); o[3]=f2bf(f0[3]);
        o[4]=f2bf(f1[0]); o[5]=f2bf(f1[1]); o[6]=f2bf(f1[2]); o[7]=f2bf(f1[3]);
        *(short8*)&xb[i0] = o;
      }
    } else {
      int wb = b - gx;                       // 0..15
      int idx = ((wb & 7) * 512 + t) * 4;    // 0..16383
      int n = idx >> 7, k = idx & 127;
      const float* src;
      if (wb < 8) src = (k < 64) ? &Wl1[n * 64 + k] : &Wr1[n * 64 + (k - 64)];
      else        src = (n < 64) ? &Wl2[n * 128 + k] : &Wr2[(n - 64) * 128 + k];
      floatx4 f = *(const floatx4*)src;
      short* dst = (wb < 8 ? wc1 : wc2) + idx;
      dst[0]=f2bf(f[0]); dst[1]=f2bf(f[1]); dst[2]=f2bf(f[2]); dst[3]=f2bf(f[3]);
    }
    return;
  }
  // ---- partition part ----
  int base = blk * TILE;
  int cnt_here = E - base; if (cnt_here > TILE) cnt_here = TILE;
  for (int i = t; i < NB; i += 512) hist[i] = 0;
  if (t == 0) smode = 1;
  __syncthreads();
  {
    const long long* e64 = (const long long*)edges;
    int nchk = E < 256 ? E : 256;
    bool ok = true;
    for (int i = t; i < nchk; i += 512) {
      long long v = e64[i];
      if (v < 0 || v >= nmax) ok = false;
    }
    if (!ok) smode = 0;   // idempotent race, fine
  }
  __syncthreads();
  bool m64 = (smode != 0);
  // ---- pass 1: load tile into registers, rank via LDS atomic ----
  unsigned val[EPT];   // payload: (d&127)<<17 | s
  unsigned aux[EPT];   // (b<<14) | rank   (rank < 16384)
  #pragma unroll
  for (int c = 0; c < EPT; ++c) {
    int idx = c * 512 + t;
    val[c] = 0; aux[c] = 0;
    if (idx < cnt_here) {
      int i = base + idx;
      int s, d;
      if (m64) { const long long* e = (const long long*)edges; s = (int)e[i]; d = (int)e[(size_t)E + i]; }
      else     { const int*       e = (const int*)edges;       s = e[i];      d = e[(size_t)E + i]; }
      int b = d >> BSH;
      int rank = atomicAdd(&hist[b], 1);
      val[c] = ((unsigned)(d & (BNODES - 1)) << 17) | (unsigned)s;
      aux[c] = ((unsigned)b << 14) | (unsigned)rank;
    }
  }
  __syncthreads();
  // ---- per-bucket global run reservation (padded) + SENT fill ----
  for (int b = t; b < NB; b += 512) {
    int cnt = hist[b];
    int gbase = 0;
    if (cnt > 0) {
      int pad = (cnt + 15) & ~15;
      gbase = b * CAP + atomicAdd(&bucket_cursor[b], pad);
      atomicAdd(&real_cnt[b], cnt);
      for (int j = cnt; j < pad; ++j) packed[gbase + j] = SENT;
    }
    gb[b] = gbase;
  }
  __syncthreads();
  // ---- direct register -> global scatter (run regions are block-contiguous) ----
  #pragma unroll
  for (int c = 0; c < EPT; ++c) {
    int idx = c * 512 + t;
    if (idx < cnt_here) {
      unsigned a = aux[c];
      packed[gb[a >> 14] + (a & 0x3FFFu)] = val[c];
    }
  }
}

// ====================== fused bucket sort + layer-1 mean aggregation (512 thr) =========
// Block b owns nodes [b*128,(b+1)*128): inline-scan ebase over real_cnt, counting-sort
// its edges into LDS elist (+ global sorted_src for agg2), then aggregate xb[src].
// 8 lanes per node, 64 nodes per chunk, 2 chunks.
__global__ __launch_bounds__(512) void bucket_sort_agg_kernel(const unsigned* __restrict__ packed,
    const int* __restrict__ bucket_cursor, const int* __restrict__ real_cnt,
    int* __restrict__ row_ptr, int* __restrict__ sorted_src,
    const short* __restrict__ feat, short* __restrict__ meanb, int N, int E) {
  __shared__ int nhist[BNODES];
  __shared__ int cur[BNODES];
  __shared__ int begs[BNODES];
  __shared__ int elist[CAP];
  __shared__ int wsum[8];
  __shared__ int redsum[8];
  int b = blockIdx.x, t = threadIdx.x;
  // ---- inline exclusive scan: eb = sum real_cnt[0..b) ----
  int partial = 0;
  for (int i = t; i < b; i += 512) partial += real_cnt[i];
  #pragma unroll
  for (int off = 1; off < 64; off <<= 1) partial += __shfl_xor(partial, off, 64);
  if ((t & 63) == 0) redsum[t >> 6] = partial;
  if (t < BNODES) nhist[t] = 0;
  if (b == 0 && t == 0) row_ptr[N] = E;
  __syncthreads();
  int eb = 0;
  #pragma unroll
  for (int i = 0; i < 8; ++i) eb += redsum[i];
  int n0 = b << BSH;
  int nn = N - n0; if (nn > BNODES) nn = BNODES;
  int rbeg = b * CAP, rcnt = bucket_cursor[b];
  // ---- per-node histogram ----
  for (int i = t; i < rcnt; i += 512) {
    unsigned p = packed[rbeg + i];
    if (p != SENT) atomicAdd(&nhist[p >> 17], 1);
  }
  __syncthreads();
  int lane = t & 63, w = t >> 6;
  int v = (t < BNODES) ? nhist[t] : 0;
  int val = v;
  #pragma unroll
  for (int off = 1; off < 64; off <<= 1) {
    int u = __shfl_up(val, off, 64);
    if (lane >= off) val += u;
  }
  if (lane == 63) wsum[w] = val;
  __syncthreads();
  int pre = (w == 1) ? wsum[0] : 0;
  int excl = pre + val - v;                 // local (bucket-relative) begin, valid t<128
  if (t < nn) { row_ptr[n0 + t] = eb + excl; cur[t] = excl; begs[t] = excl; }
  __syncthreads();
  // ---- scatter: LDS elist (for local agg) + global sorted_src (for layer-2 agg) ----
  for (int i = t; i < rcnt; i += 512) {
    unsigned p = packed[rbeg + i];
    if (p != SENT) {
      int pos = atomicAdd(&cur[p >> 17], 1);
      int s = (int)(p & 0x1FFFFu);
      elist[pos] = s;
      sorted_src[eb + pos] = s;
    }
  }
  __syncthreads();
  // ---- layer-1 mean aggregation: lane c owns cols [c*8,c*8+8) of its node ----
  int c = t & 7;
  const short* fbase = feat + c * 8;
  #pragma unroll
  for (int ch = 0; ch < 2; ++ch) {
    int ln = ch * 64 + (t >> 3);
    if (ln < nn) {
      int beg = begs[ln], end = cur[ln];    // cur = end after scatter
      floatx2 acc2[4];
      #pragma unroll
      for (int k = 0; k < 4; ++k) acc2[k] = (floatx2){0.f, 0.f};
      int e = beg;
      for (; e + 8 <= end; e += 8) {
        int s0 = elist[e],     s1 = elist[e + 1], s2 = elist[e + 2], s3 = elist[e + 3];
        int s4 = elist[e + 4], s5 = elist[e + 5], s6 = elist[e + 6], s7 = elist[e + 7];
        short8 v0 = *(const short8*)&fbase[(size_t)s0 * 64];
        short8 v1 = *(const short8*)&fbase[(size_t)s1 * 64];
        short8 v2 = *(const short8*)&fbase[(size_t)s2 * 64];
        short8 v3 = *(const short8*)&fbase[(size_t)s3 * 64];
        short8 v4 = *(const short8*)&fbase[(size_t)s4 * 64];
        short8 v5 = *(const short8*)&fbase[(size_t)s5 * 64];
        short8 v6 = *(const short8*)&fbase[(size_t)s6 * 64];
        short8 v7 = *(const short8*)&fbase[(size_t)s7 * 64];
        const unsigned* u0 = (const unsigned*)&v0;
        const unsigned* u1 = (const unsigned*)&v1;
        const unsigned* u2 = (const unsigned*)&v2;
        const unsigned* u3 = (const unsigned*)&v3;
        const unsigned* u4 = (const unsigned*)&v4;
        const unsigned* u5 = (const unsigned*)&v5;
        const unsigned* u6 = (const unsigned*)&v6;
        const unsigned* u7 = (const unsigned*)&v7;
        #pragma unroll
        for (int k = 0; k < 4; ++k) {
          floatx2 s01 = bfpair(u0[k]) + bfpair(u1[k]);
          floatx2 s23 = bfpair(u2[k]) + bfpair(u3[k]);
          floatx2 s45 = bfpair(u4[k]) + bfpair(u5[k]);
          floatx2 s67 = bfpair(u6[k]) + bfpair(u7[k]);
          acc2[k] += (s01 + s23) + (s45 + s67);
        }
      }
      for (; e < end; ++e) {
        short8 vv = *(const short8*)&fbase[(size_t)elist[e] * 64];
        const unsigned* uu = (const unsigned*)&vv;
        #pragma unroll
        for (int k = 0; k < 4; ++k) acc2[k] += bfpair(uu[k]);
      }
      float inv = 1.f / fmaxf((float)(end - beg), 1.f);
      short8 o;
      #pragma unroll
      for (int k = 0; k < 4; ++k) {
        o[2 * k]     = f2bf(acc2[k][0] * inv);
        o[2 * k + 1] = f2bf(acc2[k][1] * inv);
      }
      *(short8*)&meanb[(size_t)(n0 + ln) * 64 + c * 8] = o;
    }
  }
}

// ====================== layer-2 mean aggregation + epilogue (D=64) =====================
// 8 lanes per node (8 nodes/wave): lane c owns cols [c*8, c*8+8). Serial edge walk,
// int4 srcs loads + 8-deep gather ILP + float2 accumulate. out = mean + bias + r (fp32).
__global__ __launch_bounds__(256) void agg_epi_kernel(const short* __restrict__ feat,
                                                      const int* __restrict__ row_ptr,
                                                      const int* __restrict__ srcs,
                                                      const float* __restrict__ rbuf,
                                                      const float* __restrict__ bias,
                                                      float* __restrict__ outf, int N) {
  int node = blockIdx.x * 32 + (threadIdx.x >> 3);
  if (node >= N) return;
  int c = threadIdx.x & 7;
  const short* fbase = feat + c * 8;
  int beg = row_ptr[node], end = row_ptr[node + 1];
  floatx2 acc2[4];
  #pragma unroll
  for (int k = 0; k < 4; ++k) acc2[k] = (floatx2){0.f, 0.f};
  int e = beg;
  for (; e + 8 <= end; e += 8) {
    intx4 sa = *(const intx4*)&srcs[e];
    intx4 sb = *(const intx4*)&srcs[e + 4];
    short8 v0 = *(const short8*)&fbase[(size_t)sa[0] * 64];
    short8 v1 = *(const short8*)&fbase[(size_t)sa[1] * 64];
    short8 v2 = *(const short8*)&fbase[(size_t)sa[2] * 64];
    short8 v3 = *(const short8*)&fbase[(size_t)sa[3] * 64];
    short8 v4 = *(const short8*)&fbase[(size_t)sb[0] * 64];
    short8 v5 = *(const short8*)&fbase[(size_t)sb[1] * 64];
    short8 v6 = *(const short8*)&fbase[(size_t)sb[2] * 64];
    short8 v7 = *(const short8*)&fbase[(size_t)sb[3] * 64];
    const unsigned* u0 = (const unsigned*)&v0;
    const unsigned* u1 = (const unsigned*)&v1;
    const unsigned* u2 = (const unsigned*)&v2;
    const unsigned* u3 = (const unsigned*)&v3;
    const unsigned* u4 = (const unsigned*)&v4;
    const unsigned* u5 = (const unsigned*)&v5;
    const unsigned* u6 = (const unsigned*)&v6;
    const unsigned* u7 = (const unsigned*)&v7;
    #pragma unroll
    for (int k = 0; k < 4; ++k) {
      floatx2 s01 = bfpair(u0[k]) + bfpair(u1[k]);
      floatx2 s23 = bfpair(u2[k]) + bfpair(u3[k]);
      floatx2 s45 = bfpair(u4[k]) + bfpair(u5[k]);
      floatx2 s67 = bfpair(u6[k]) + bfpair(u7[k]);
      acc2[k] += (s01 + s23) + (s45 + s67);
    }
  }
  for (; e + 4 <= end; e += 4) {
    intx4 sa = *(const intx4*)&srcs[e];
    short8 v0 = *(const short8*)&fbase[(size_t)sa[0] * 64];
    short8 v1 = *(const short8*)&fbase[(size_t)sa[1] * 64];
    short8 v2 = *(const short8*)&fbase[(size_t)sa[2] * 64];
    short8 v3 = *(const short8*)&fbase[(size_t)sa[3] * 64];
    const unsigned* u0 = (const unsigned*)&v0;
    const unsigned* u1 = (const unsigned*)&v1;
    const unsigned* u2 = (const unsigned*)&v2;
    const unsigned* u3 = (const unsigned*)&v3;
    #pragma unroll
    for (int k = 0; k < 4; ++k) {
      floatx2 s01 = bfpair(u0[k]) + bfpair(u1[k]);
      floatx2 s23 = bfpair(u2[k]) + bfpair(u3[k]);
      acc2[k] += s01 + s23;
    }
  }
  for (; e < end; ++e) {
    short8 v = *(const short8*)&fbase[(size_t)srcs[e] * 64];
    const unsigned* u = (const unsigned*)&v;
    #pragma unroll
    for (int k = 0; k < 4; ++k) acc2[k] += bfpair(u[k]);
  }
  float acc[8];
  #pragma unroll
  for (int k = 0; k < 4; ++k) { acc[2 * k] = acc2[k][0]; acc[2 * k + 1] = acc2[k][1]; }
  float inv = 1.f / fmaxf((float)(end - beg), 1.f);
  floatx4 b0 = *(const floatx4*)&bias[c * 8];
  floatx4 b1 = *(const floatx4*)&bias[c * 8 + 4];
  floatx4 r0 = *(const floatx4*)&rbuf[(size_t)node * 64 + c * 8];
  floatx4 r1 = *(const floatx4*)&rbuf[(size_t)node * 64 + c * 8 + 4];
  floatx4 o0, o1;
  #pragma unroll
  for (int j = 0; j < 4; ++j) {
    o0[j] = acc[j] * inv + b0[j] + r0[j];
    o1[j] = acc[4 + j] * inv + b1[j] + r1[j];
  }
  *(floatx4*)&outf[(size_t)node * 64 + c * 8]     = o0;
  *(floatx4*)&outf[(size_t)node * 64 + c * 8 + 4] = o1;
}

// ====================== fused bf16 MFMA GEMM: layer1 -> (LDS h) -> layer2 ==============
// 128 rows/block (2 m-tiles per wave) to amortize the 64KB weight staging.
// Phase 1: h = relu([mean|x] @ wc1^T + bl1) -> LDS Hs (never hits HBM).
// Phase 2: restage Ws with wc2; cols 0..63 -> g bf16, cols 64..127 -> r fp32.
// A-frag: lane holds A[m=lane&15][k=q*8..q*8+7]; C/D: col=lane&15, row=q*4+reg (m89).
// Row-pad 136 shorts: 2-way bank alias on ds_read_b128 = free (m136).
__global__ __launch_bounds__(256) void fused_gemm_kernel(
    const short* __restrict__ Aa, const short* __restrict__ Ab,
    const short* __restrict__ wc1, const short* __restrict__ wc2,
    const float* __restrict__ bias1,
    short* __restrict__ Cg, float* __restrict__ Cr, int M)
{
  __shared__ short Ws[128][136];
  __shared__ short Hs[128][136];
  int t = threadIdx.x;
  // ---- stage wc1 ----
  #pragma unroll
  for (int i = 0; i < 8; ++i) {
    int idx = i * 256 + t;
    int r = idx >> 4, c8 = (idx & 15) * 8;
    *(short8*)&Ws[r][c8] = *(const short8*)&wc1[r * 128 + c8];
  }
  __syncthreads();
  int wv = t >> 6, lane = t & 63, q = lane >> 4, l15 = lane & 15;
  int m0 = blockIdx.x * 128 + wv * 32;
  floatx4 acc[2][8];
  #pragma unroll
  for (int mt = 0; mt < 2; ++mt)
    #pragma unroll
    for (int nt = 0; nt < 8; ++nt) acc[mt][nt] = (floatx4){0.f, 0.f, 0.f, 0.f};
  // ---- phase 1: [mean | x] @ wc1^T ----
  #pragma unroll
  for (int ko = 0; ko < 4; ++ko) {
    const short* Asrc = (ko < 2) ? Aa : Ab;
    short8 a[2];
    #pragma unroll
    for (int mt = 0; mt < 2; ++mt) {
      int row = m0 + mt * 16 + l15;
      a[mt] = (short8){0, 0, 0, 0, 0, 0, 0, 0};
      if (row < M) a[mt] = *(const short8*)&Asrc[(size_t)row * 64 + (ko & 1) * 32 + q * 8];
    }
    #pragma unroll
    for (int nt = 0; nt < 8; ++nt) {
      short8 bfr = *(const short8*)&Ws[nt * 16 + l15][ko * 32 + q * 8];
      acc[0][nt] = __builtin_amdgcn_mfma_f32_16x16x32_bf16(a[0], bfr, acc[0][nt], 0, 0, 0);
      acc[1][nt] = __builtin_amdgcn_mfma_f32_16x16x32_bf16(a[1], bfr, acc[1][nt], 0, 0, 0);
    }
  }
  // ---- epilogue 1: relu(+bias) -> Hs (block-local rows) ----
  #pragma unroll
  for (int mt = 0; mt < 2; ++mt) {
    #pragma unroll
    for (int nt = 0; nt < 8; ++nt) {
      int n = nt * 16 + l15;
      float bv = bias1[n];
      #pragma unroll
      for (int r2 = 0; r2 < 4; ++r2) {
        int lr = wv * 32 + mt * 16 + q * 4 + r2;   // block-local row
        float v = fmaxf(acc[mt][nt][r2] + bv, 0.f);
        Hs[lr][n] = f2bf(v);
      }
    }
  }
  __syncthreads();               // Ws reads done everywhere; Hs visible
  // ---- restage Ws with wc2 ----
  #pragma unroll
  for (int i = 0; i < 8; ++i) {
    int idx = i * 256 + t;
    int r = idx >> 4, c8 = (idx & 15) * 8;
    *(short8*)&Ws[r][c8] = *(const short8*)&wc2[r * 128 + c8];
  }
  __syncthreads();
  // ---- phase 2: h @ wc2^T (A from LDS) ----
  #pragma unroll
  for (int mt = 0; mt < 2; ++mt)
    #pragma unroll
    for (int nt = 0; nt < 8; ++nt) acc[mt][nt] = (floatx4){0.f, 0.f, 0.f, 0.f};
  #pragma unroll
  for (int ko = 0; ko < 4; ++ko) {
    short8 a[2];
    #pragma unroll
    for (int mt = 0; mt < 2; ++mt)
      a[mt] = *(const short8*)&Hs[wv * 32 + mt * 16 + l15][ko * 32 + q * 8];
    #pragma unroll
    for (int nt = 0; nt < 8; ++nt) {
      short8 bfr = *(const short8*)&Ws[nt * 16 + l15][ko * 32 + q * 8];
      acc[0][nt] = __builtin_amdgcn_mfma_f32_16x16x32_bf16(a[0], bfr, acc[0][nt], 0, 0, 0);
      acc[1][nt] = __builtin_amdgcn_mfma_f32_16x16x32_bf16(a[1], bfr, acc[1][nt], 0, 0, 0);
    }
  }
  // ---- epilogue 2: cols 0..63 -> Cg bf16, cols 64..127 -> Cr fp32 ----
  #pragma unroll
  for (int mt = 0; mt < 2; ++mt) {
    #pragma unroll
    for (int nt = 0; nt < 8; ++nt) {
      int n = nt * 16 + l15;
      #pragma unroll
      for (int r2 = 0; r2 < 4; ++r2) {
        int mr = m0 + mt * 16 + q * 4 + r2;
        if (mr >= M) continue;
        float v = acc[mt][nt][r2];
        if (nt < 4) Cg[(size_t)mr * 64 + n] = f2bf(v);
        else        Cr[(size_t)mr * 64 + (n - 64)] = v;
      }
    }
  }
}

// ====================== launch ======================
extern "C" void kernel_launch(void* const* d_in, const int* in_sizes, int n_in,
                              void* d_out, int out_size, void* d_ws, size_t ws_size,
                              hipStream_t stream) {
  const float* x   = (const float*)d_in[0];
  const void*  ei  = d_in[1];
  const float* Wl1 = (const float*)d_in[2];
  const float* bl1 = (const float*)d_in[3];
  const float* Wr1 = (const float*)d_in[4];
  const float* Wl2 = (const float*)d_in[5];
  const float* bl2 = (const float*)d_in[6];
  const float* Wr2 = (const float*)d_in[7];
  int N = in_sizes[0] / DIN;
  int E = in_sizes[1] / 2;
  int NB = (N + BNODES - 1) / BNODES;

  char* w = (char*)d_ws;
  size_t off = 0;
  auto alloc = [&](size_t bytes) -> void* {
    void* p = w + off;
    off += (bytes + 255) & ~(size_t)255;
    return p;
  };
  int*      bcur       = (int*)alloc((size_t)NB * 8);      // [cursor | real_cnt]
  int*      rcnt       = bcur + NB;
  int*      row_ptr    = (int*)alloc(((size_t)N + 1) * 4);
  unsigned* packed     = (unsigned*)alloc((size_t)NB * CAP * 4);
  int*      sorted_src = (int*)alloc((size_t)E * 4);
  short*    xb         = (short*)alloc((size_t)N * 64 * 2);
  short*    meanb      = (short*)alloc((size_t)N * 64 * 2);  // layer-1 mean, reused as g
  float*    rbuf       = (float*)alloc((size_t)N * 64 * 4);
  short*    wc1        = (short*)alloc(128 * 128 * 2);
  short*    wc2        = (short*)alloc(128 * 128 * 2);
  (void)ws_size; (void)n_in; (void)out_size;

  hipMemsetAsync(bcur, 0, (size_t)NB * 8, stream);

  int nx = N * DIN;
  int gx = (nx / 8 + 511) / 512;
  int gP = (E + TILE - 1) / TILE;
  part_prep_kernel<<<gP + gx + 16, 512, 0, stream>>>(ei, (long long)N, bcur, rcnt, packed,
                                                     E, NB, x, Wl1, Wr1, Wl2, Wr2,
                                                     xb, wc1, wc2, nx, gP, gx);

  bucket_sort_agg_kernel<<<NB, 512, 0, stream>>>(packed, bcur, rcnt, row_ptr, sorted_src,
                                                 xb, meanb, N, E);

  int gm = (N + 127) / 128;
  fused_gemm_kernel<<<gm, 256, 0, stream>>>(meanb, xb, wc1, wc2, bl1, meanb, rbuf, N);

  int gN32 = (N + 31) / 32;  // 8 lanes per node, 32 nodes per 256-thread block
  agg_epi_kernel<<<gN32, 256, 0, stream>>>(meanb, row_ptr, sorted_src, rbuf, bl2, (float*)d_out, N);
}

// Round 14
// 196.097 us; speedup vs baseline: 6.1837x; 1.0218x over previous
//
#include <hip/hip_runtime.h>
#include <cstdint>
#include <cstddef>

typedef __attribute__((ext_vector_type(8))) short short8;
typedef __attribute__((ext_vector_type(4))) float floatx4;
typedef __attribute__((ext_vector_type(2))) float floatx2;
typedef __attribute__((ext_vector_type(4))) int intx4;

static constexpr int DIN  = 64;
static constexpr int DHID = 128;
static constexpr int BSH  = 7;               // 128 nodes per dst-bucket
static constexpr int BNODES = 1 << BSH;
static constexpr int TILE = 8192;            // edges per partition block
static constexpr int CAP  = 4096;            // bucket region capacity
static constexpr int EPT  = TILE / 512;      // 16 edges per thread (register-held)
static constexpr unsigned SENT = 0xFFFFFFFFu;

__device__ inline short f2bf(float f) {      // RNE float->bf16
  unsigned u = __float_as_uint(f);
  u += 0x7FFF + ((u >> 16) & 1);
  return (short)(u >> 16);
}
__device__ inline float bf2f(short s) {
  return __uint_as_float(((unsigned)(unsigned short)s) << 16);
}
// one u32 holding bf16 pair (elem 2k low, 2k+1 high) -> 2 f32
__device__ inline floatx2 bfpair(unsigned u) {
  floatx2 r;
  r[0] = __uint_as_float(u << 16);
  r[1] = __uint_as_float(u & 0xFFFF0000u);
  return r;
}

// ====================== fused partition + prep (512 threads, staged writes) ============
// blocks [0,gP): edge partition, TILE=8192, EPT=16 register-held; LDS-staged
// run-coalesced writes to packed (padded-to-16 runs, SENT sentinels).
// Measured-best configuration (r11: 196.1us). Partition ablation complete:
// occupancy/write-pattern/atomic-count all at floor.
// blocks [gP,gP+gx): x cast. blocks [gP+gx, gP+gx+16): weight concat.
// wc1[n][k] = [Wl1 | Wr1] (K-concat), wc2[n][k] = rows [Wl2 ; Wr2] (N-concat).
__global__ __launch_bounds__(512) void part_prep_kernel(const void* edges, long long nmax,
    int* __restrict__ bucket_cursor, int* __restrict__ real_cnt,
    unsigned* __restrict__ packed, int E, int NB,
    const float* __restrict__ x,
    const float* __restrict__ Wl1, const float* __restrict__ Wr1,
    const float* __restrict__ Wl2, const float* __restrict__ Wr2,
    short* __restrict__ xb, short* __restrict__ wc1, short* __restrict__ wc2,
    int nx, int gP, int gx)
{
  __shared__ unsigned sval[TILE];           // 32KB: locally bucket-sorted payloads
  __shared__ unsigned short sbid[TILE];     // 16KB: bucket id per sorted slot
  __shared__ int hist[1024];
  __shared__ int lbase[1024];               // block-local exclusive prefix
  __shared__ int gb[1024];                  // global run base per bucket
  __shared__ int wsum[8];
  __shared__ int smode;
  int t = threadIdx.x;
  int blk = blockIdx.x;
  if (blk >= gP) {                       // ---- prep part ----
    int b = blk - gP;
    if (b < gx) {
      int i0 = (b * 512 + t) * 8;
      if (i0 < nx) {  // nx % 8 == 0
        floatx4 f0 = *(const floatx4*)&x[i0];
        floatx4 f1 = *(const floatx4*)&x[i0 + 4];
        short8 o;
        o[0]=f2bf(f0[0]); o[1]=f2bf(f0[1]); o[2]=f2bf(f0[2]); o[3]=f2bf(f0[3]);
        o[4]=f2bf(f1[0]); o[5]=f2bf(f1[1]); o[6]=f2bf(f1[2]); o[7]=f2bf(f1[3]);
        *(short8*)&xb[i0] = o;
      }
    } else {
      int wb = b - gx;                       // 0..15
      int idx = ((wb & 7) * 512 + t) * 4;    // 0..16383
      int n = idx >> 7, k = idx & 127;
      const float* src;
      if (wb < 8) src = (k < 64) ? &Wl1[n * 64 + k] : &Wr1[n * 64 + (k - 64)];
      else        src = (n < 64) ? &Wl2[n * 128 + k] : &Wr2[(n - 64) * 128 + k];
      floatx4 f = *(const floatx4*)src;
      short* dst = (wb < 8 ? wc1 : wc2) + idx;
      dst[0]=f2bf(f[0]); dst[1]=f2bf(f[1]); dst[2]=f2bf(f[2]); dst[3]=f2bf(f[3]);
    }
    return;
  }
  // ---- partition part ----
  int base = blk * TILE;
  int cnt_here = E - base; if (cnt_here > TILE) cnt_here = TILE;
  for (int i = t; i < NB; i += 512) hist[i] = 0;
  if (t == 0) smode = 1;
  __syncthreads();
  {
    const long long* e64 = (const long long*)edges;
    int nchk = E < 256 ? E : 256;
    bool ok = true;
    for (int i = t; i < nchk; i += 512) {
      long long v = e64[i];
      if (v < 0 || v >= nmax) ok = false;
    }
    if (!ok) smode = 0;   // idempotent race, fine
  }
  __syncthreads();
  bool m64 = (smode != 0);
  // ---- pass 1: load tile into registers, rank via LDS atomic ----
  unsigned val[EPT];   // payload: (d&127)<<17 | s
  unsigned aux[EPT];   // (b<<13) | rank   (rank < 8192)
  #pragma unroll
  for (int c = 0; c < EPT; ++c) {
    int idx = c * 512 + t;
    val[c] = 0; aux[c] = 0;
    if (idx < cnt_here) {
      int i = base + idx;
      int s, d;
      if (m64) { const long long* e = (const long long*)edges; s = (int)e[i]; d = (int)e[(size_t)E + i]; }
      else     { const int*       e = (const int*)edges;       s = e[i];      d = e[(size_t)E + i]; }
      int b = d >> BSH;
      int rank = atomicAdd(&hist[b], 1);
      val[c] = ((unsigned)(d & (BNODES - 1)) << 17) | (unsigned)s;
      aux[c] = ((unsigned)b << 13) | (unsigned)rank;
    }
  }
  __syncthreads();
  // ---- block scan of hist -> lbase; padded global run reservation + SENT fill ----
  {
    int i0 = t * 2;
    int v2[2]; int s = 0;
    #pragma unroll
    for (int c = 0; c < 2; ++c) { int idx = i0 + c; v2[c] = (idx < NB) ? hist[idx] : 0; s += v2[c]; }
    int lane = t & 63, w = t >> 6;
    int vv = s;
    #pragma unroll
    for (int off = 1; off < 64; off <<= 1) {
      int u = __shfl_up(vv, off, 64);
      if (lane >= off) vv += u;
    }
    if (lane == 63) wsum[w] = vv;
    __syncthreads();
    int wpre = 0;
    for (int ww = 0; ww < w; ++ww) wpre += wsum[ww];
    int run = wpre + vv - s;
    #pragma unroll
    for (int c = 0; c < 2; ++c) {
      int idx = i0 + c;
      if (idx < NB) {
        int cnt = v2[c];
        lbase[idx] = run;
        int gbase = 0;
        if (cnt > 0) {
          int pad = (cnt + 15) & ~15;
          gbase = idx * CAP + atomicAdd(&bucket_cursor[idx], pad);
          atomicAdd(&real_cnt[idx], cnt);
          for (int j = cnt; j < pad; ++j) packed[gbase + j] = SENT;
        }
        gb[idx] = gbase;
        run += cnt;
      }
    }
  }
  __syncthreads();
  // ---- LDS scatter into bucket-sorted order ----
  #pragma unroll
  for (int c = 0; c < EPT; ++c) {
    int idx = c * 512 + t;
    if (idx < cnt_here) {
      int b = (int)(aux[c] >> 13);
      int r = (int)(aux[c] & 0x1FFFu);
      int p = lbase[b] + r;
      sval[p] = val[c];
      sbid[p] = (unsigned short)b;
    }
  }
  __syncthreads();
  // ---- linear, run-coalesced global write ----
  #pragma unroll
  for (int c = 0; c < EPT; ++c) {
    int i = c * 512 + t;
    if (i < cnt_here) {
      int b = (int)sbid[i];
      packed[gb[b] + (i - lbase[b])] = sval[i];
    }
  }
}

// ====================== fused bucket sort + layer-1 mean aggregation (512 thr) =========
// Block b owns nodes [b*128,(b+1)*128): inline-scan ebase over real_cnt, counting-sort
// its edges into LDS elist (+ global sorted_src for agg2), then aggregate xb[src].
// 8 lanes per node, 64 nodes per chunk, 2 chunks.
__global__ __launch_bounds__(512) void bucket_sort_agg_kernel(const unsigned* __restrict__ packed,
    const int* __restrict__ bucket_cursor, const int* __restrict__ real_cnt,
    int* __restrict__ row_ptr, int* __restrict__ sorted_src,
    const short* __restrict__ feat, short* __restrict__ meanb, int N, int E) {
  __shared__ int nhist[BNODES];
  __shared__ int cur[BNODES];
  __shared__ int begs[BNODES];
  __shared__ int elist[CAP];
  __shared__ int wsum[8];
  __shared__ int redsum[8];
  int b = blockIdx.x, t = threadIdx.x;
  // ---- inline exclusive scan: eb = sum real_cnt[0..b) ----
  int partial = 0;
  for (int i = t; i < b; i += 512) partial += real_cnt[i];
  #pragma unroll
  for (int off = 1; off < 64; off <<= 1) partial += __shfl_xor(partial, off, 64);
  if ((t & 63) == 0) redsum[t >> 6] = partial;
  if (t < BNODES) nhist[t] = 0;
  if (b == 0 && t == 0) row_ptr[N] = E;
  __syncthreads();
  int eb = 0;
  #pragma unroll
  for (int i = 0; i < 8; ++i) eb += redsum[i];
  int n0 = b << BSH;
  int nn = N - n0; if (nn > BNODES) nn = BNODES;
  int rbeg = b * CAP, rcnt = bucket_cursor[b];
  // ---- per-node histogram ----
  for (int i = t; i < rcnt; i += 512) {
    unsigned p = packed[rbeg + i];
    if (p != SENT) atomicAdd(&nhist[p >> 17], 1);
  }
  __syncthreads();
  int lane = t & 63, w = t >> 6;
  int v = (t < BNODES) ? nhist[t] : 0;
  int val = v;
  #pragma unroll
  for (int off = 1; off < 64; off <<= 1) {
    int u = __shfl_up(val, off, 64);
    if (lane >= off) val += u;
  }
  if (lane == 63) wsum[w] = val;
  __syncthreads();
  int pre = (w == 1) ? wsum[0] : 0;
  int excl = pre + val - v;                 // local (bucket-relative) begin, valid t<128
  if (t < nn) { row_ptr[n0 + t] = eb + excl; cur[t] = excl; begs[t] = excl; }
  __syncthreads();
  // ---- scatter: LDS elist (for local agg) + global sorted_src (for layer-2 agg) ----
  for (int i = t; i < rcnt; i += 512) {
    unsigned p = packed[rbeg + i];
    if (p != SENT) {
      int pos = atomicAdd(&cur[p >> 17], 1);
      int s = (int)(p & 0x1FFFFu);
      elist[pos] = s;
      sorted_src[eb + pos] = s;
    }
  }
  __syncthreads();
  // ---- layer-1 mean aggregation: lane c owns cols [c*8,c*8+8) of its node ----
  int c = t & 7;
  const short* fbase = feat + c * 8;
  #pragma unroll
  for (int ch = 0; ch < 2; ++ch) {
    int ln = ch * 64 + (t >> 3);
    if (ln < nn) {
      int beg = begs[ln], end = cur[ln];    // cur = end after scatter
      floatx2 acc2[4];
      #pragma unroll
      for (int k = 0; k < 4; ++k) acc2[k] = (floatx2){0.f, 0.f};
      int e = beg;
      for (; e + 8 <= end; e += 8) {
        int s0 = elist[e],     s1 = elist[e + 1], s2 = elist[e + 2], s3 = elist[e + 3];
        int s4 = elist[e + 4], s5 = elist[e + 5], s6 = elist[e + 6], s7 = elist[e + 7];
        short8 v0 = *(const short8*)&fbase[(size_t)s0 * 64];
        short8 v1 = *(const short8*)&fbase[(size_t)s1 * 64];
        short8 v2 = *(const short8*)&fbase[(size_t)s2 * 64];
        short8 v3 = *(const short8*)&fbase[(size_t)s3 * 64];
        short8 v4 = *(const short8*)&fbase[(size_t)s4 * 64];
        short8 v5 = *(const short8*)&fbase[(size_t)s5 * 64];
        short8 v6 = *(const short8*)&fbase[(size_t)s6 * 64];
        short8 v7 = *(const short8*)&fbase[(size_t)s7 * 64];
        const unsigned* u0 = (const unsigned*)&v0;
        const unsigned* u1 = (const unsigned*)&v1;
        const unsigned* u2 = (const unsigned*)&v2;
        const unsigned* u3 = (const unsigned*)&v3;
        const unsigned* u4 = (const unsigned*)&v4;
        const unsigned* u5 = (const unsigned*)&v5;
        const unsigned* u6 = (const unsigned*)&v6;
        const unsigned* u7 = (const unsigned*)&v7;
        #pragma unroll
        for (int k = 0; k < 4; ++k) {
          floatx2 s01 = bfpair(u0[k]) + bfpair(u1[k]);
          floatx2 s23 = bfpair(u2[k]) + bfpair(u3[k]);
          floatx2 s45 = bfpair(u4[k]) + bfpair(u5[k]);
          floatx2 s67 = bfpair(u6[k]) + bfpair(u7[k]);
          acc2[k] += (s01 + s23) + (s45 + s67);
        }
      }
      for (; e < end; ++e) {
        short8 vv = *(const short8*)&fbase[(size_t)elist[e] * 64];
        const unsigned* uu = (const unsigned*)&vv;
        #pragma unroll
        for (int k = 0; k < 4; ++k) acc2[k] += bfpair(uu[k]);
      }
      float inv = 1.f / fmaxf((float)(end - beg), 1.f);
      short8 o;
      #pragma unroll
      for (int k = 0; k < 4; ++k) {
        o[2 * k]     = f2bf(acc2[k][0] * inv);
        o[2 * k + 1] = f2bf(acc2[k][1] * inv);
      }
      *(short8*)&meanb[(size_t)(n0 + ln) * 64 + c * 8] = o;
    }
  }
}

// ====================== layer-2 mean aggregation + epilogue (D=64) =====================
// 8 lanes per node (8 nodes/wave): lane c owns cols [c*8, c*8+8). Serial edge walk,
// int4 srcs loads + 8-deep gather ILP + float2 accumulate. out = mean + bias + r (fp32).
__global__ __launch_bounds__(256) void agg_epi_kernel(const short* __restrict__ feat,
                                                      const int* __restrict__ row_ptr,
                                                      const int* __restrict__ srcs,
                                                      const float* __restrict__ rbuf,
                                                      const float* __restrict__ bias,
                                                      float* __restrict__ outf, int N) {
  int node = blockIdx.x * 32 + (threadIdx.x >> 3);
  if (node >= N) return;
  int c = threadIdx.x & 7;
  const short* fbase = feat + c * 8;
  int beg = row_ptr[node], end = row_ptr[node + 1];
  floatx2 acc2[4];
  #pragma unroll
  for (int k = 0; k < 4; ++k) acc2[k] = (floatx2){0.f, 0.f};
  int e = beg;
  for (; e + 8 <= end; e += 8) {
    intx4 sa = *(const intx4*)&srcs[e];
    intx4 sb = *(const intx4*)&srcs[e + 4];
    short8 v0 = *(const short8*)&fbase[(size_t)sa[0] * 64];
    short8 v1 = *(const short8*)&fbase[(size_t)sa[1] * 64];
    short8 v2 = *(const short8*)&fbase[(size_t)sa[2] * 64];
    short8 v3 = *(const short8*)&fbase[(size_t)sa[3] * 64];
    short8 v4 = *(const short8*)&fbase[(size_t)sb[0] * 64];
    short8 v5 = *(const short8*)&fbase[(size_t)sb[1] * 64];
    short8 v6 = *(const short8*)&fbase[(size_t)sb[2] * 64];
    short8 v7 = *(const short8*)&fbase[(size_t)sb[3] * 64];
    const unsigned* u0 = (const unsigned*)&v0;
    const unsigned* u1 = (const unsigned*)&v1;
    const unsigned* u2 = (const unsigned*)&v2;
    const unsigned* u3 = (const unsigned*)&v3;
    const unsigned* u4 = (const unsigned*)&v4;
    const unsigned* u5 = (const unsigned*)&v5;
    const unsigned* u6 = (const unsigned*)&v6;
    const unsigned* u7 = (const unsigned*)&v7;
    #pragma unroll
    for (int k = 0; k < 4; ++k) {
      floatx2 s01 = bfpair(u0[k]) + bfpair(u1[k]);
      floatx2 s23 = bfpair(u2[k]) + bfpair(u3[k]);
      floatx2 s45 = bfpair(u4[k]) + bfpair(u5[k]);
      floatx2 s67 = bfpair(u6[k]) + bfpair(u7[k]);
      acc2[k] += (s01 + s23) + (s45 + s67);
    }
  }
  for (; e + 4 <= end; e += 4) {
    intx4 sa = *(const intx4*)&srcs[e];
    short8 v0 = *(const short8*)&fbase[(size_t)sa[0] * 64];
    short8 v1 = *(const short8*)&fbase[(size_t)sa[1] * 64];
    short8 v2 = *(const short8*)&fbase[(size_t)sa[2] * 64];
    short8 v3 = *(const short8*)&fbase[(size_t)sa[3] * 64];
    const unsigned* u0 = (const unsigned*)&v0;
    const unsigned* u1 = (const unsigned*)&v1;
    const unsigned* u2 = (const unsigned*)&v2;
    const unsigned* u3 = (const unsigned*)&v3;
    #pragma unroll
    for (int k = 0; k < 4; ++k) {
      floatx2 s01 = bfpair(u0[k]) + bfpair(u1[k]);
      floatx2 s23 = bfpair(u2[k]) + bfpair(u3[k]);
      acc2[k] += s01 + s23;
    }
  }
  for (; e < end; ++e) {
    short8 v = *(const short8*)&fbase[(size_t)srcs[e] * 64];
    const unsigned* u = (const unsigned*)&v;
    #pragma unroll
    for (int k = 0; k < 4; ++k) acc2[k] += bfpair(u[k]);
  }
  float acc[8];
  #pragma unroll
  for (int k = 0; k < 4; ++k) { acc[2 * k] = acc2[k][0]; acc[2 * k + 1] = acc2[k][1]; }
  float inv = 1.f / fmaxf((float)(end - beg), 1.f);
  floatx4 b0 = *(const floatx4*)&bias[c * 8];
  floatx4 b1 = *(const floatx4*)&bias[c * 8 + 4];
  floatx4 r0 = *(const floatx4*)&rbuf[(size_t)node * 64 + c * 8];
  floatx4 r1 = *(const floatx4*)&rbuf[(size_t)node * 64 + c * 8 + 4];
  floatx4 o0, o1;
  #pragma unroll
  for (int j = 0; j < 4; ++j) {
    o0[j] = acc[j] * inv + b0[j] + r0[j];
    o1[j] = acc[4 + j] * inv + b1[j] + r1[j];
  }
  *(floatx4*)&outf[(size_t)node * 64 + c * 8]     = o0;
  *(floatx4*)&outf[(size_t)node * 64 + c * 8 + 4] = o1;
}

// ====================== fused bf16 MFMA GEMM: layer1 -> (LDS h) -> layer2 ==============
// 128 rows/block (2 m-tiles per wave) to amortize the 64KB weight staging.
// Phase 1: h = relu([mean|x] @ wc1^T + bl1) -> LDS Hs (never hits HBM).
// Phase 2: restage Ws with wc2; cols 0..63 -> g bf16, cols 64..127 -> r fp32.
// A-frag: lane holds A[m=lane&15][k=q*8..q*8+7]; C/D: col=lane&15, row=q*4+reg (m89).
// Row-pad 136 shorts: 2-way bank alias on ds_read_b128 = free (m136).
__global__ __launch_bounds__(256) void fused_gemm_kernel(
    const short* __restrict__ Aa, const short* __restrict__ Ab,
    const short* __restrict__ wc1, const short* __restrict__ wc2,
    const float* __restrict__ bias1,
    short* __restrict__ Cg, float* __restrict__ Cr, int M)
{
  __shared__ short Ws[128][136];
  __shared__ short Hs[128][136];
  int t = threadIdx.x;
  // ---- stage wc1 ----
  #pragma unroll
  for (int i = 0; i < 8; ++i) {
    int idx = i * 256 + t;
    int r = idx >> 4, c8 = (idx & 15) * 8;
    *(short8*)&Ws[r][c8] = *(const short8*)&wc1[r * 128 + c8];
  }
  __syncthreads();
  int wv = t >> 6, lane = t & 63, q = lane >> 4, l15 = lane & 15;
  int m0 = blockIdx.x * 128 + wv * 32;
  floatx4 acc[2][8];
  #pragma unroll
  for (int mt = 0; mt < 2; ++mt)
    #pragma unroll
    for (int nt = 0; nt < 8; ++nt) acc[mt][nt] = (floatx4){0.f, 0.f, 0.f, 0.f};
  // ---- phase 1: [mean | x] @ wc1^T ----
  #pragma unroll
  for (int ko = 0; ko < 4; ++ko) {
    const short* Asrc = (ko < 2) ? Aa : Ab;
    short8 a[2];
    #pragma unroll
    for (int mt = 0; mt < 2; ++mt) {
      int row = m0 + mt * 16 + l15;
      a[mt] = (short8){0, 0, 0, 0, 0, 0, 0, 0};
      if (row < M) a[mt] = *(const short8*)&Asrc[(size_t)row * 64 + (ko & 1) * 32 + q * 8];
    }
    #pragma unroll
    for (int nt = 0; nt < 8; ++nt) {
      short8 bfr = *(const short8*)&Ws[nt * 16 + l15][ko * 32 + q * 8];
      acc[0][nt] = __builtin_amdgcn_mfma_f32_16x16x32_bf16(a[0], bfr, acc[0][nt], 0, 0, 0);
      acc[1][nt] = __builtin_amdgcn_mfma_f32_16x16x32_bf16(a[1], bfr, acc[1][nt], 0, 0, 0);
    }
  }
  // ---- epilogue 1: relu(+bias) -> Hs (block-local rows) ----
  #pragma unroll
  for (int mt = 0; mt < 2; ++mt) {
    #pragma unroll
    for (int nt = 0; nt < 8; ++nt) {
      int n = nt * 16 + l15;
      float bv = bias1[n];
      #pragma unroll
      for (int r2 = 0; r2 < 4; ++r2) {
        int lr = wv * 32 + mt * 16 + q * 4 + r2;   // block-local row
        float v = fmaxf(acc[mt][nt][r2] + bv, 0.f);
        Hs[lr][n] = f2bf(v);
      }
    }
  }
  __syncthreads();               // Ws reads done everywhere; Hs visible
  // ---- restage Ws with wc2 ----
  #pragma unroll
  for (int i = 0; i < 8; ++i) {
    int idx = i * 256 + t;
    int r = idx >> 4, c8 = (idx & 15) * 8;
    *(short8*)&Ws[r][c8] = *(const short8*)&wc2[r * 128 + c8];
  }
  __syncthreads();
  // ---- phase 2: h @ wc2^T (A from LDS) ----
  #pragma unroll
  for (int mt = 0; mt < 2; ++mt)
    #pragma unroll
    for (int nt = 0; nt < 8; ++nt) acc[mt][nt] = (floatx4){0.f, 0.f, 0.f, 0.f};
  #pragma unroll
  for (int ko = 0; ko < 4; ++ko) {
    short8 a[2];
    #pragma unroll
    for (int mt = 0; mt < 2; ++mt)
      a[mt] = *(const short8*)&Hs[wv * 32 + mt * 16 + l15][ko * 32 + q * 8];
    #pragma unroll
    for (int nt = 0; nt < 8; ++nt) {
      short8 bfr = *(const short8*)&Ws[nt * 16 + l15][ko * 32 + q * 8];
      acc[0][nt] = __builtin_amdgcn_mfma_f32_16x16x32_bf16(a[0], bfr, acc[0][nt], 0, 0, 0);
      acc[1][nt] = __builtin_amdgcn_mfma_f32_16x16x32_bf16(a[1], bfr, acc[1][nt], 0, 0, 0);
    }
  }
  // ---- epilogue 2: cols 0..63 -> Cg bf16, cols 64..127 -> Cr fp32 ----
  #pragma unroll
  for (int mt = 0; mt < 2; ++mt) {
    #pragma unroll
    for (int nt = 0; nt < 8; ++nt) {
      int n = nt * 16 + l15;
      #pragma unroll
      for (int r2 = 0; r2 < 4; ++r2) {
        int mr = m0 + mt * 16 + q * 4 + r2;
        if (mr >= M) continue;
        float v = acc[mt][nt][r2];
        if (nt < 4) Cg[(size_t)mr * 64 + n] = f2bf(v);
        else        Cr[(size_t)mr * 64 + (n - 64)] = v;
      }
    }
  }
}

// ====================== launch ======================
extern "C" void kernel_launch(void* const* d_in, const int* in_sizes, int n_in,
                              void* d_out, int out_size, void* d_ws, size_t ws_size,
                              hipStream_t stream) {
  const float* x   = (const float*)d_in[0];
  const void*  ei  = d_in[1];
  const float* Wl1 = (const float*)d_in[2];
  const float* bl1 = (const float*)d_in[3];
  const float* Wr1 = (const float*)d_in[4];
  const float* Wl2 = (const float*)d_in[5];
  const float* bl2 = (const float*)d_in[6];
  const float* Wr2 = (const float*)d_in[7];
  int N = in_sizes[0] / DIN;
  int E = in_sizes[1] / 2;
  int NB = (N + BNODES - 1) / BNODES;

  char* w = (char*)d_ws;
  size_t off = 0;
  auto alloc = [&](size_t bytes) -> void* {
    void* p = w + off;
    off += (bytes + 255) & ~(size_t)255;
    return p;
  };
  int*      bcur       = (int*)alloc((size_t)NB * 8);      // [cursor | real_cnt]
  int*      rcnt       = bcur + NB;
  int*      row_ptr    = (int*)alloc(((size_t)N + 1) * 4);
  unsigned* packed     = (unsigned*)alloc((size_t)NB * CAP * 4);
  int*      sorted_src = (int*)alloc((size_t)E * 4);
  short*    xb         = (short*)alloc((size_t)N * 64 * 2);
  short*    meanb      = (short*)alloc((size_t)N * 64 * 2);  // layer-1 mean, reused as g
  float*    rbuf       = (float*)alloc((size_t)N * 64 * 4);
  short*    wc1        = (short*)alloc(128 * 128 * 2);
  short*    wc2        = (short*)alloc(128 * 128 * 2);
  (void)ws_size; (void)n_in; (void)out_size;

  hipMemsetAsync(bcur, 0, (size_t)NB * 8, stream);

  int nx = N * DIN;
  int gx = (nx / 8 + 511) / 512;
  int gP = (E + TILE - 1) / TILE;
  part_prep_kernel<<<gP + gx + 16, 512, 0, stream>>>(ei, (long long)N, bcur, rcnt, packed,
                                                     E, NB, x, Wl1, Wr1, Wl2, Wr2,
                                                     xb, wc1, wc2, nx, gP, gx);

  bucket_sort_agg_kernel<<<NB, 512, 0, stream>>>(packed, bcur, rcnt, row_ptr, sorted_src,
                                                 xb, meanb, N, E);

  int gm = (N + 127) / 128;
  fused_gemm_kernel<<<gm, 256, 0, stream>>>(meanb, xb, wc1, wc2, bl1, meanb, rbuf, N);

  int gN32 = (N + 31) / 32;  // 8 lanes per node, 32 nodes per 256-thread block
  agg_epi_kernel<<<gN32, 256, 0, stream>>>(meanb, row_ptr, sorted_src, rbuf, bl2, (float*)d_out, N);
}